// Round 5
// baseline (775.207 us; speedup 1.0000x reference)
//
#include <hip/hip_runtime.h>
#include <math.h>
#include <stdint.h>

#define PI2 6.28318530717958647692f

typedef __bf16 bf16x8 __attribute__((ext_vector_type(8)));
typedef float f32x4 __attribute__((ext_vector_type(4)));

typedef __attribute__((address_space(1))) const void gvoid_t;
typedef __attribute__((address_space(3))) void lvoid_t;

__device__ __forceinline__ void g2l16(const void* g, void* l) {
    __builtin_amdgcn_global_load_lds(
        reinterpret_cast<gvoid_t*>(reinterpret_cast<uintptr_t>(g)),
        reinterpret_cast<lvoid_t*>(reinterpret_cast<uintptr_t>(l)),
        16, 0, 0);
}

__device__ __forceinline__ short f2bf(float f) {
    unsigned u = __float_as_uint(f);
    u += 0x7FFFu + ((u >> 16) & 1u);          // round-to-nearest-even
    return (short)(u >> 16);
}

__device__ __forceinline__ unsigned pack2bf(float a, float b) {
    return (unsigned)(unsigned short)f2bf(a) |
           ((unsigned)(unsigned short)f2bf(b) << 16);
}

__device__ __forceinline__ float bflo(unsigned v) { return __uint_as_float(v << 16); }
__device__ __forceinline__ float bfhi(unsigned v) { return __uint_as_float(v & 0xFFFF0000u); }

// ---------------------------------------------------------------------------
// Fused aux kernel, 8 elements (one uint4 of bf16) per thread.
// Element regions (all boundaries divisible by 8; halves 512/1024-aligned so
// one thread's 8 elements never straddle a source split):
//   [0,        4194304): x_bf  = bf16(x)                    1024x4096
//   [4194304, 12582912): B1    = DFT basis n=4096           2048x4096
//   [12582912,16777216): Vcat  = [Vr|Vi]                    2048x2048
//   [16777216,18874368): B2    = DFT basis n=2048 * S[k]    1024x2048
//   [18874368,23068672): Ucat  = [Ur|Ui]                    4096x1024
//   [23068672,23070720): zero 1024 split-K tile counters (one extra block)
// ---------------------------------------------------------------------------
__global__ __launch_bounds__(256) void aux_all8(
    const float* __restrict__ x,
    const float* __restrict__ Ur, const float* __restrict__ Ui,
    const float* __restrict__ S,
    const float* __restrict__ Vr, const float* __restrict__ Vi,
    short* __restrict__ x_bf, short* __restrict__ B1,
    short* __restrict__ Vcat, short* __restrict__ B2,
    short* __restrict__ Ucat, int* __restrict__ cnt)
{
    unsigned gid = blockIdx.x * 256u + threadIdx.x;
    unsigned i8  = gid * 8u;
    if (i8 < 4194304u) {
        const float4* s4 = (const float4*)(x + i8);
        float4 a = s4[0], b = s4[1];
        uint4 o = {pack2bf(a.x, a.y), pack2bf(a.z, a.w),
                   pack2bf(b.x, b.y), pack2bf(b.z, b.w)};
        *(uint4*)(x_bf + i8) = o;
    } else if (i8 < 12582912u) {
        unsigned i = i8 - 4194304u;
        int c = i >> 12, j0 = i & 4095;
        const float inv_n = 1.0f / 4096.0f;
        float v[8];
        if (c < 1024) {
            if (c == 0) {
                #pragma unroll
                for (int u = 0; u < 8; ++u) v[u] = inv_n;
            } else {
                #pragma unroll
                for (int u = 0; u < 8; ++u) {
                    int t = (c * (j0 + u)) & 4095;
                    v[u] = 2.0f * inv_n * cosf((float)t * (PI2 / 4096.0f));
                }
            }
        } else {
            int m = c - 1024;
            #pragma unroll
            for (int u = 0; u < 8; ++u) {
                int t = (m * (j0 + u)) & 4095;
                v[u] = -2.0f * inv_n * sinf((float)t * (PI2 / 4096.0f));
            }
        }
        uint4 o = {pack2bf(v[0], v[1]), pack2bf(v[2], v[3]),
                   pack2bf(v[4], v[5]), pack2bf(v[6], v[7])};
        *(uint4*)(B1 + i) = o;
    } else if (i8 < 16777216u) {
        unsigned i = i8 - 12582912u;
        int t = i >> 11, c = i & 2047;
        const float* src = (c < 1024) ? (Vr + t * 1024 + c)
                                      : (Vi + t * 1024 + (c - 1024));
        float4 a = ((const float4*)src)[0], b = ((const float4*)src)[1];
        uint4 o = {pack2bf(a.x, a.y), pack2bf(a.z, a.w),
                   pack2bf(b.x, b.y), pack2bf(b.z, b.w)};
        *(uint4*)(Vcat + i) = o;
    } else if (i8 < 18874368u) {
        unsigned i = i8 - 16777216u;
        int p = i >> 11, k0 = i & 2047;
        float4 s0 = *(const float4*)(S + k0);
        float4 s1 = *(const float4*)(S + k0 + 4);
        float sv[8] = {s0.x, s0.y, s0.z, s0.w, s1.x, s1.y, s1.z, s1.w};
        const float inv_n = 1.0f / 2048.0f;
        float v[8];
        if (p < 512) {
            if (p == 0) {
                #pragma unroll
                for (int u = 0; u < 8; ++u) v[u] = inv_n;
            } else {
                #pragma unroll
                for (int u = 0; u < 8; ++u) {
                    int t = (p * (k0 + u)) & 2047;
                    v[u] = 2.0f * inv_n * cosf((float)t * (PI2 / 2048.0f));
                }
            }
        } else {
            int q = p - 512;
            #pragma unroll
            for (int u = 0; u < 8; ++u) {
                int t = (q * (k0 + u)) & 2047;
                v[u] = -2.0f * inv_n * sinf((float)t * (PI2 / 2048.0f));
            }
        }
        #pragma unroll
        for (int u = 0; u < 8; ++u) v[u] *= sv[u];
        uint4 o = {pack2bf(v[0], v[1]), pack2bf(v[2], v[3]),
                   pack2bf(v[4], v[5]), pack2bf(v[6], v[7])};
        *(uint4*)(B2 + i) = o;
    } else if (i8 < 23068672u) {
        unsigned i = i8 - 18874368u;
        int o_ = i >> 10, c = i & 1023;
        const float* src = (c < 512) ? (Ur + o_ * 512 + c)
                                     : (Ui + o_ * 512 + (c - 512));
        float4 a = ((const float4*)src)[0], b = ((const float4*)src)[1];
        uint4 o = {pack2bf(a.x, a.y), pack2bf(a.z, a.w),
                   pack2bf(b.x, b.y), pack2bf(b.z, b.w)};
        *(uint4*)(Ucat + i) = o;
    } else {
        // one trailing block zeroes the 1024 tile counters
        ((int4*)cnt)[threadIdx.x] = (int4){0, 0, 0, 0};
    }
}

// ---------------------------------------------------------------------------
// Split-K bf16 MFMA NT-GEMM with FUSED final reduction (last-block-done).
// BK=64, 128x128 tile, 256 threads, 32 KB LDS, 4 blocks/CU.
// Each z-block writes its bf16 partial plane, fences, bumps the tile counter;
// the last z-block for a tile reduces all SK planes and writes the final
// output (bf16, or f32+bias when OUT_F32).
// LDS XOR-swizzle as in round 4 (global-side swizzle, linear LDS dst).
// ---------------------------------------------------------------------------
template <bool OUT_F32>
__global__ __launch_bounds__(256, 4) void gemm_bt_sk64_fused(
    const short* __restrict__ A, int lda,
    const short* __restrict__ B, int ldb,
    short* __restrict__ P, int ldc, size_t planeMN,
    int Kpart, int* __restrict__ cnt, int SK,
    void* __restrict__ Out, const float* __restrict__ bias)
{
    __shared__ __align__(16) short As[128 * 64];
    __shared__ __align__(16) short Bs[128 * 64];
    __shared__ int sLast;

    const int tid  = threadIdx.x;
    const int wave = tid >> 6;
    const int lane = tid & 63;
    const int bm   = blockIdx.y << 7;
    const int bn   = blockIdx.x << 7;
    const int wm   = (wave >> 1) << 6;
    const int wn   = (wave & 1) << 6;
    const int l16  = lane & 15;
    const int quad = lane >> 4;
    const int rk   = l16 & 7;

    const short* Az = A + (size_t)blockIdx.z * Kpart;
    const short* Bz = B + (size_t)blockIdx.z * Kpart;
    short* C = P + (size_t)blockIdx.z * planeMN;

    f32x4 acc[4][4];
    #pragma unroll
    for (int i = 0; i < 4; ++i)
        #pragma unroll
        for (int j = 0; j < 4; ++j)
            acc[i][j] = (f32x4){0.f, 0.f, 0.f, 0.f};

    int aoff[4], boff[4], loff[4];
    #pragma unroll
    for (int p = 0; p < 4; ++p) {
        int L   = p * 256 + wave * 64 + lane;
        int row = L >> 3;
        int swz = (L & 7) ^ (row & 7);
        aoff[p] = (bm + row) * lda + swz * 8;
        boff[p] = (bn + row) * ldb + swz * 8;
        loff[p] = L * 8;
    }

    for (int k0 = 0; k0 < Kpart; k0 += 64) {
        __syncthreads();
        #pragma unroll
        for (int p = 0; p < 4; ++p) g2l16(Az + aoff[p] + k0, As + loff[p]);
        #pragma unroll
        for (int p = 0; p < 4; ++p) g2l16(Bz + boff[p] + k0, Bs + loff[p]);
        __syncthreads();

        #pragma unroll
        for (int h = 0; h < 2; ++h) {
            const int cs8 = ((((h << 2) | quad) ^ rk) << 3);
            bf16x8 b[4];
            #pragma unroll
            for (int nt = 0; nt < 4; ++nt)
                b[nt] = *(const bf16x8*)(Bs + (wn + nt * 16 + l16) * 64 + cs8);
            #pragma unroll
            for (int mt = 0; mt < 4; ++mt) {
                bf16x8 a = *(const bf16x8*)(As + (wm + mt * 16 + l16) * 64 + cs8);
                #pragma unroll
                for (int nt = 0; nt < 4; ++nt)
                    acc[mt][nt] = __builtin_amdgcn_mfma_f32_16x16x32_bf16(
                        a, b[nt], acc[mt][nt], 0, 0, 0);
            }
        }
    }

    // ---- write bf16 partial plane (C/D layout: col=lane&15, row=quad*4+r)
    #pragma unroll
    for (int nt = 0; nt < 4; ++nt) {
        int col = bn + wn + nt * 16 + l16;
        #pragma unroll
        for (int mt = 0; mt < 4; ++mt) {
            int rowb = bm + wm + mt * 16 + quad * 4;
            #pragma unroll
            for (int r = 0; r < 4; ++r)
                C[(size_t)(rowb + r) * ldc + col] = f2bf(acc[mt][nt][r]);
        }
    }

    // ---- last-block-done reduction
    __threadfence();                       // release: partials visible device-wide
    __syncthreads();
    if (tid == 0) {
        int tile = blockIdx.y * gridDim.x + blockIdx.x;
        sLast = (atomicAdd(cnt + tile, 1) == SK - 1);
    }
    __syncthreads();
    if (!sLast) return;
    __threadfence();                       // acquire: see all planes

    // 128x128 tile = 2048 uint4 chunks of 8 bf16; 8 chunks/thread.
    for (int q = tid; q < 2048; q += 256) {
        int row = q >> 4, cc = q & 15;
        size_t off = (size_t)(bm + row) * ldc + bn + cc * 8;
        float s[8] = {0, 0, 0, 0, 0, 0, 0, 0};
        for (int z = 0; z < SK; ++z) {
            uint4 v = *(const uint4*)(P + (size_t)z * planeMN + off);
            s[0] += bflo(v.x); s[1] += bfhi(v.x);
            s[2] += bflo(v.y); s[3] += bfhi(v.y);
            s[4] += bflo(v.z); s[5] += bfhi(v.z);
            s[6] += bflo(v.w); s[7] += bfhi(v.w);
        }
        if (OUT_F32) {
            const float4* b4 = (const float4*)(bias + bn + cc * 8);
            float4 b0 = b4[0], b1 = b4[1];
            float* o = (float*)Out + off;
            ((float4*)o)[0] = (float4){s[0] + b0.x, s[1] + b0.y, s[2] + b0.z, s[3] + b0.w};
            ((float4*)o)[1] = (float4){s[4] + b1.x, s[5] + b1.y, s[6] + b1.z, s[7] + b1.w};
        } else {
            uint4 o = {pack2bf(s[0], s[1]), pack2bf(s[2], s[3]),
                       pack2bf(s[4], s[5]), pack2bf(s[6], s[7])};
            *(uint4*)((short*)Out + off) = o;
        }
    }
}

// ---------------------------------------------------------------------------
// Fallback direct GEMM (round-2 proven path) if ws is too small
// ---------------------------------------------------------------------------
template <bool OUT_F32>
__global__ __launch_bounds__(256) void gemm_bt_bf16(
    const short* __restrict__ A, int lda,
    const short* __restrict__ B, int ldb,
    void* __restrict__ Cv, int ldc,
    const float* __restrict__ bias, int K)
{
    __shared__ __align__(16) short As[128 * 32];
    __shared__ __align__(16) short Bs[128 * 32];

    const int tid  = threadIdx.x;
    const int wave = tid >> 6;
    const int lane = tid & 63;
    const int bm   = blockIdx.y << 7;
    const int bn   = blockIdx.x << 7;
    const int wm   = (wave >> 1) << 6;
    const int wn   = (wave & 1) << 6;
    const int l16  = lane & 15;
    const int quad = lane >> 4;

    f32x4 acc[4][4];
    #pragma unroll
    for (int i = 0; i < 4; ++i)
        #pragma unroll
        for (int j = 0; j < 4; ++j)
            acc[i][j] = (f32x4){0.f, 0.f, 0.f, 0.f};

    const int L0 = wave * 64 + lane;
    const int r0 = L0 >> 2, c0 = (L0 & 3) << 3;
    const int L1 = 256 + L0;
    const int r1 = L1 >> 2, c1 = (L1 & 3) << 3;

    const short* Ag0 = A + (size_t)(bm + r0) * lda + c0;
    const short* Ag1 = A + (size_t)(bm + r1) * lda + c1;
    const short* Bg0 = B + (size_t)(bn + r0) * ldb + c0;
    const short* Bg1 = B + (size_t)(bn + r1) * ldb + c1;
    short* Al0 = As + (wave * 64) * 8;
    short* Al1 = As + (256 + wave * 64) * 8;
    short* Bl0 = Bs + (wave * 64) * 8;
    short* Bl1 = Bs + (256 + wave * 64) * 8;

    for (int k0 = 0; k0 < K; k0 += 32) {
        __syncthreads();
        g2l16(Ag0 + k0, Al0);
        g2l16(Ag1 + k0, Al1);
        g2l16(Bg0 + k0, Bl0);
        g2l16(Bg1 + k0, Bl1);
        __syncthreads();

        bf16x8 a[4], b[4];
        #pragma unroll
        for (int mt = 0; mt < 4; ++mt)
            a[mt] = *(const bf16x8*)(As + (wm + mt * 16 + l16) * 32 + quad * 8);
        #pragma unroll
        for (int nt = 0; nt < 4; ++nt)
            b[nt] = *(const bf16x8*)(Bs + (wn + nt * 16 + l16) * 32 + quad * 8);
        #pragma unroll
        for (int mt = 0; mt < 4; ++mt)
            #pragma unroll
            for (int nt = 0; nt < 4; ++nt)
                acc[mt][nt] = __builtin_amdgcn_mfma_f32_16x16x32_bf16(
                    a[mt], b[nt], acc[mt][nt], 0, 0, 0);
    }

    if (OUT_F32) {
        float* C = (float*)Cv;
        #pragma unroll
        for (int nt = 0; nt < 4; ++nt) {
            int col = bn + wn + nt * 16 + l16;
            float bv = bias ? bias[col] : 0.f;
            #pragma unroll
            for (int mt = 0; mt < 4; ++mt) {
                int rowb = bm + wm + mt * 16 + quad * 4;
                #pragma unroll
                for (int r = 0; r < 4; ++r)
                    C[(size_t)(rowb + r) * ldc + col] = acc[mt][nt][r] + bv;
            }
        }
    } else {
        short* C = (short*)Cv;
        #pragma unroll
        for (int nt = 0; nt < 4; ++nt) {
            int col = bn + wn + nt * 16 + l16;
            #pragma unroll
            for (int mt = 0; mt < 4; ++mt) {
                int rowb = bm + wm + mt * 16 + quad * 4;
                #pragma unroll
                for (int r = 0; r < 4; ++r)
                    C[(size_t)(rowb + r) * ldc + col] = f2bf(acc[mt][nt][r]);
            }
        }
    }
}

extern "C" void kernel_launch(void* const* d_in, const int* in_sizes, int n_in,
                              void* d_out, int out_size, void* d_ws, size_t ws_size,
                              hipStream_t stream) {
    const float* x    = (const float*)d_in[0];
    const float* Ur   = (const float*)d_in[1];
    const float* Ui   = (const float*)d_in[2];
    const float* S    = (const float*)d_in[3];
    const float* Vr   = (const float*)d_in[4];
    const float* Vi   = (const float*)d_in[5];
    const float* bias = (const float*)d_in[6];
    float* out = (float*)d_out;

    short* ws   = (short*)d_ws;
    short* x_bf = ws;                                  // 1024*4096
    short* B1   = x_bf + (size_t)1024 * 4096;          // 2048*4096
    short* Vcat = B1   + (size_t)2048 * 4096;          // 2048*2048
    short* B2   = Vcat + (size_t)2048 * 2048;          // 1024*2048
    short* Ucat = B2   + (size_t)1024 * 2048;          // 4096*1024
    short* Xp   = Ucat + (size_t)4096 * 1024;          // 1024*2048
    short* T1   = Xp   + (size_t)1024 * 2048;          // 1024*2048
    short* Yp   = T1   + (size_t)1024 * 2048;          // 1024*1024
    short* Pp   = Yp   + (size_t)1024 * 1024;          // partials: 16.78M shorts
    int*   cnt  = (int*)(Pp + (size_t)8 * 1024 * 2048); // 1024 tile counters

    const size_t need = (size_t)((char*)(cnt + 1024) - (char*)d_ws);

    if (ws_size >= need) {
        aux_all8<<<dim3(11265), 256, 0, stream>>>(
            x, Ur, Ui, S, Vr, Vi, x_bf, B1, Vcat, B2, Ucat, cnt);

        // Stage 1: X' = x @ B1^T   (1024x2048, K=4096, SK=8 -> 1024 blocks)
        gemm_bt_sk64_fused<false><<<dim3(16, 8, 8), 256, 0, stream>>>(
            x_bf, 4096, B1, 4096, Pp, 2048, (size_t)1024 * 2048, 512,
            cnt, 8, Xp, nullptr);

        // Stage 2: T1 = X' @ Vcat^T (1024x2048, K=2048, SK=8 -> 1024 blocks)
        gemm_bt_sk64_fused<false><<<dim3(16, 8, 8), 256, 0, stream>>>(
            Xp, 2048, Vcat, 2048, Pp, 2048, (size_t)1024 * 2048, 256,
            cnt + 128, 8, T1, nullptr);

        // Stage 3: Y' = T1 @ B2^T  (1024x1024, K=2048, SK=8 -> 512 blocks)
        gemm_bt_sk64_fused<false><<<dim3(8, 8, 8), 256, 0, stream>>>(
            T1, 2048, B2, 2048, Pp, 1024, (size_t)1024 * 1024, 256,
            cnt + 256, 8, Yp, nullptr);

        // Stage 4: out = Y' @ Ucat^T + bias (1024x4096, K=1024, SK=4 -> 1024)
        gemm_bt_sk64_fused<true><<<dim3(32, 8, 4), 256, 0, stream>>>(
            Yp, 1024, Ucat, 1024, Pp, 4096, (size_t)1024 * 4096, 256,
            cnt + 320, 4, out, bias);
    } else {
        aux_all8<<<dim3(11265), 256, 0, stream>>>(
            x, Ur, Ui, S, Vr, Vi, x_bf, B1, Vcat, B2, Ucat, cnt);
        gemm_bt_bf16<false><<<dim3(16, 8), 256, 0, stream>>>(
            x_bf, 4096, B1, 4096, Xp, 2048, nullptr, 4096);
        gemm_bt_bf16<false><<<dim3(16, 8), 256, 0, stream>>>(
            Xp, 2048, Vcat, 2048, T1, 2048, nullptr, 2048);
        gemm_bt_bf16<false><<<dim3(8, 8), 256, 0, stream>>>(
            T1, 2048, B2, 2048, Yp, 1024, nullptr, 2048);
        gemm_bt_bf16<true><<<dim3(32, 8), 256, 0, stream>>>(
            Yp, 1024, Ucat, 1024, out, 4096, bias, 1024);
    }
}

// Round 6
// 210.881 us; speedup vs baseline: 3.6760x; 3.6760x over previous
//
#include <hip/hip_runtime.h>
#include <math.h>
#include <stdint.h>

#define PI2 6.28318530717958647692f

typedef __bf16 bf16x8 __attribute__((ext_vector_type(8)));
typedef float f32x4 __attribute__((ext_vector_type(4)));

typedef __attribute__((address_space(1))) const void gvoid_t;
typedef __attribute__((address_space(3))) void lvoid_t;

__device__ __forceinline__ void g2l16(const void* g, void* l) {
    __builtin_amdgcn_global_load_lds(
        reinterpret_cast<gvoid_t*>(reinterpret_cast<uintptr_t>(g)),
        reinterpret_cast<lvoid_t*>(reinterpret_cast<uintptr_t>(l)),
        16, 0, 0);
}

__device__ __forceinline__ short f2bf(float f) {
    unsigned u = __float_as_uint(f);
    u += 0x7FFFu + ((u >> 16) & 1u);          // round-to-nearest-even
    return (short)(u >> 16);
}

__device__ __forceinline__ unsigned pack2bf(float a, float b) {
    return (unsigned)(unsigned short)f2bf(a) |
           ((unsigned)(unsigned short)f2bf(b) << 16);
}

__device__ __forceinline__ float bflo(unsigned v) { return __uint_as_float(v << 16); }
__device__ __forceinline__ float bfhi(unsigned v) { return __uint_as_float(v & 0xFFFF0000u); }

// ---------------------------------------------------------------------------
// Fused aux kernel, 8 elements (one uint4 of bf16) per thread.
//   [0,        4194304): x_bf = bf16(x)                      1024x4096
//   [4194304, 12582912): B1   = DFT basis n=4096             2048x4096
//   [12582912,16777216): Vcat = [Vr|Vi]                      2048x2048
//   [16777216,18874368): B2t  = DFT basis n=2048 (T) * S[k]  2048x1024
//   [18874368,23068672): Ucat = [Ur|Ui]                      4096x1024
// 2,883,584 threads = 11,264 blocks. All region/source-split boundaries are
// 8-aligned, so one thread's 8 elements never straddle a split.
// ---------------------------------------------------------------------------
__global__ __launch_bounds__(256) void aux_all8(
    const float* __restrict__ x,
    const float* __restrict__ Ur, const float* __restrict__ Ui,
    const float* __restrict__ S,
    const float* __restrict__ Vr, const float* __restrict__ Vi,
    short* __restrict__ x_bf, short* __restrict__ B1,
    short* __restrict__ Vcat, short* __restrict__ B2t,
    short* __restrict__ Ucat)
{
    unsigned gid = blockIdx.x * 256u + threadIdx.x;
    unsigned i8  = gid * 8u;
    if (i8 < 4194304u) {
        const float4* s4 = (const float4*)(x + i8);
        float4 a = s4[0], b = s4[1];
        uint4 o = {pack2bf(a.x, a.y), pack2bf(a.z, a.w),
                   pack2bf(b.x, b.y), pack2bf(b.z, b.w)};
        *(uint4*)(x_bf + i8) = o;
    } else if (i8 < 12582912u) {
        unsigned i = i8 - 4194304u;
        int c = i >> 12, j0 = i & 4095;
        const float inv_n = 1.0f / 4096.0f;
        float v[8];
        if (c < 1024) {
            if (c == 0) {
                #pragma unroll
                for (int u = 0; u < 8; ++u) v[u] = inv_n;
            } else {
                #pragma unroll
                for (int u = 0; u < 8; ++u) {
                    int t = (c * (j0 + u)) & 4095;
                    v[u] = 2.0f * inv_n * cosf((float)t * (PI2 / 4096.0f));
                }
            }
        } else {
            int m = c - 1024;
            #pragma unroll
            for (int u = 0; u < 8; ++u) {
                int t = (m * (j0 + u)) & 4095;
                v[u] = -2.0f * inv_n * sinf((float)t * (PI2 / 4096.0f));
            }
        }
        uint4 o = {pack2bf(v[0], v[1]), pack2bf(v[2], v[3]),
                   pack2bf(v[4], v[5]), pack2bf(v[6], v[7])};
        *(uint4*)(B1 + i) = o;
    } else if (i8 < 16777216u) {
        unsigned i = i8 - 12582912u;
        int t = i >> 11, c = i & 2047;
        const float* src = (c < 1024) ? (Vr + t * 1024 + c)
                                      : (Vi + t * 1024 + (c - 1024));
        float4 a = ((const float4*)src)[0], b = ((const float4*)src)[1];
        uint4 o = {pack2bf(a.x, a.y), pack2bf(a.z, a.w),
                   pack2bf(b.x, b.y), pack2bf(b.z, b.w)};
        *(uint4*)(Vcat + i) = o;
    } else if (i8 < 18874368u) {
        // B2t[k][p] = basis2(p, k) * S[k]   (2048 rows k, 1024 cols p)
        unsigned i = i8 - 16777216u;
        int k = i >> 10, p0 = i & 1023;
        float sk = S[k];
        const float inv_n = 1.0f / 2048.0f;
        float v[8];
        #pragma unroll
        for (int u = 0; u < 8; ++u) {
            int p = p0 + u;
            float val;
            if (p == 0) val = inv_n;
            else if (p < 512) {
                int t = (p * k) & 2047;
                val = 2.0f * inv_n * cosf((float)t * (PI2 / 2048.0f));
            } else {
                int q = p - 512;
                int t = (q * k) & 2047;
                val = -2.0f * inv_n * sinf((float)t * (PI2 / 2048.0f));
            }
            v[u] = val * sk;
        }
        uint4 o = {pack2bf(v[0], v[1]), pack2bf(v[2], v[3]),
                   pack2bf(v[4], v[5]), pack2bf(v[6], v[7])};
        *(uint4*)(B2t + i) = o;
    } else {
        unsigned i = i8 - 18874368u;
        int o_ = i >> 10, c = i & 1023;
        const float* src = (c < 512) ? (Ur + o_ * 512 + c)
                                     : (Ui + o_ * 512 + (c - 512));
        float4 a = ((const float4*)src)[0], b = ((const float4*)src)[1];
        uint4 o = {pack2bf(a.x, a.y), pack2bf(a.z, a.w),
                   pack2bf(b.x, b.y), pack2bf(b.z, b.w)};
        *(uint4*)(Ucat + i) = o;
    }
}

// ---------------------------------------------------------------------------
// Shared 128x128 MFMA tile core, BK=64, XOR-swizzled LDS (round-4 proven).
// ---------------------------------------------------------------------------
__device__ __forceinline__ void tile_core(
    const short* __restrict__ A, int lda,
    const short* __restrict__ B, int ldb, int K,
    short* As, short* Bs, int bm, int bn, f32x4 (&acc)[4][4])
{
    const int tid  = threadIdx.x;
    const int wave = tid >> 6;
    const int lane = tid & 63;
    const int wm   = (wave >> 1) << 6;
    const int wn   = (wave & 1) << 6;
    const int l16  = lane & 15;
    const int quad = lane >> 4;
    const int rk   = l16 & 7;

    int aoff[4], boff[4], loff[4];
    #pragma unroll
    for (int p = 0; p < 4; ++p) {
        int L   = p * 256 + wave * 64 + lane;
        int row = L >> 3;
        int swz = (L & 7) ^ (row & 7);
        aoff[p] = (bm + row) * lda + swz * 8;
        boff[p] = (bn + row) * ldb + swz * 8;
        loff[p] = L * 8;
    }

    for (int k0 = 0; k0 < K; k0 += 64) {
        __syncthreads();
        #pragma unroll
        for (int p = 0; p < 4; ++p) g2l16(A + aoff[p] + k0, As + loff[p]);
        #pragma unroll
        for (int p = 0; p < 4; ++p) g2l16(B + boff[p] + k0, Bs + loff[p]);
        __syncthreads();

        #pragma unroll
        for (int h = 0; h < 2; ++h) {
            const int cs8 = ((((h << 2) | quad) ^ rk) << 3);
            bf16x8 b[4];
            #pragma unroll
            for (int nt = 0; nt < 4; ++nt)
                b[nt] = *(const bf16x8*)(Bs + (wn + nt * 16 + l16) * 64 + cs8);
            #pragma unroll
            for (int mt = 0; mt < 4; ++mt) {
                bf16x8 a = *(const bf16x8*)(As + (wm + mt * 16 + l16) * 64 + cs8);
                #pragma unroll
                for (int nt = 0; nt < 4; ++nt)
                    acc[mt][nt] = __builtin_amdgcn_mfma_f32_16x16x32_bf16(
                        a, b[nt], acc[mt][nt], 0, 0, 0);
            }
        }
    }
}

__device__ __forceinline__ void store_tile_bf16(
    f32x4 (&acc)[4][4], short* __restrict__ C, int ldc, int bm, int bn)
{
    const int tid  = threadIdx.x;
    const int wave = tid >> 6;
    const int lane = tid & 63;
    const int wm   = (wave >> 1) << 6;
    const int wn   = (wave & 1) << 6;
    const int l16  = lane & 15;
    const int quad = lane >> 4;
    #pragma unroll
    for (int nt = 0; nt < 4; ++nt) {
        int col = bn + wn + nt * 16 + l16;
        #pragma unroll
        for (int mt = 0; mt < 4; ++mt) {
            int rowb = bm + wm + mt * 16 + quad * 4;
            #pragma unroll
            for (int r = 0; r < 4; ++r)
                C[(size_t)(rowb + r) * ldc + col] = f2bf(acc[mt][nt][r]);
        }
    }
}

// ---------------------------------------------------------------------------
// Merged dispatch: z<8 -> stage-1 split-K partials (X' = x @ B1^T);
//                  z>=8 -> M2 = Ucat @ B2t^T (= U*S, 4096x2048, K=1024, direct)
// grid (16, 8, 12) = 1536 blocks.
// ---------------------------------------------------------------------------
__global__ __launch_bounds__(256, 4) void gemm_s1_m2(
    const short* __restrict__ x_bf, const short* __restrict__ B1,
    short* __restrict__ Pp,
    const short* __restrict__ Ucat, const short* __restrict__ B2t,
    short* __restrict__ M2)
{
    __shared__ __align__(16) short As[128 * 64];
    __shared__ __align__(16) short Bs[128 * 64];

    f32x4 acc[4][4];
    #pragma unroll
    for (int i = 0; i < 4; ++i)
        #pragma unroll
        for (int j = 0; j < 4; ++j)
            acc[i][j] = (f32x4){0.f, 0.f, 0.f, 0.f};

    const int z = blockIdx.z;
    if (z < 8) {
        // stage 1: 1024x2048 tiles, Kpart=512
        const int bm = blockIdx.y << 7;
        const int bn = blockIdx.x << 7;
        tile_core(x_bf + z * 512, 4096, B1 + z * 512, 4096, 512,
                  As, Bs, bm, bn, acc);
        store_tile_bf16(acc, Pp + (size_t)z * 1024 * 2048, 2048, bm, bn);
    } else {
        // M2: 4096x2048 output, K=1024, no split-K
        const int bm = (blockIdx.y + ((z - 8) << 3)) << 7;   // row tile in [0,32)
        const int bn = blockIdx.x << 7;                      // col tile in [0,16)
        tile_core(Ucat, 1024, B2t, 1024, 1024, As, Bs, bm, bn, acc);
        store_tile_bf16(acc, M2, 2048, bm, bn);
    }
}

// ---------------------------------------------------------------------------
// Plain split-K GEMM into bf16 partial planes (round-4 proven, no fusion)
// ---------------------------------------------------------------------------
__global__ __launch_bounds__(256, 4) void gemm_sk(
    const short* __restrict__ A, int lda,
    const short* __restrict__ B, int ldb,
    short* __restrict__ P, int ldc, size_t planeMN, int Kpart)
{
    __shared__ __align__(16) short As[128 * 64];
    __shared__ __align__(16) short Bs[128 * 64];

    f32x4 acc[4][4];
    #pragma unroll
    for (int i = 0; i < 4; ++i)
        #pragma unroll
        for (int j = 0; j < 4; ++j)
            acc[i][j] = (f32x4){0.f, 0.f, 0.f, 0.f};

    const int bm = blockIdx.y << 7;
    const int bn = blockIdx.x << 7;
    const int z  = blockIdx.z;
    tile_core(A + (size_t)z * Kpart, lda, B + (size_t)z * Kpart, ldb, Kpart,
              As, Bs, bm, bn, acc);
    store_tile_bf16(acc, P + (size_t)z * planeMN, ldc, bm, bn);
}

// ---------------------------------------------------------------------------
// Reduce SK bf16 partial planes -> bf16
// ---------------------------------------------------------------------------
__global__ __launch_bounds__(256) void reduce_bf(const short* __restrict__ P,
                                                 size_t MN, int SK,
                                                 short* __restrict__ out) {
    size_t i = blockIdx.x * 256u + threadIdx.x;
    const uint4* P4 = (const uint4*)P;
    size_t stride = MN >> 3;
    float s[8] = {0,0,0,0,0,0,0,0};
    for (int z = 0; z < SK; ++z) {
        uint4 v = P4[(size_t)z * stride + i];
        s[0] += bflo(v.x); s[1] += bfhi(v.x);
        s[2] += bflo(v.y); s[3] += bfhi(v.y);
        s[4] += bflo(v.z); s[5] += bfhi(v.z);
        s[6] += bflo(v.w); s[7] += bfhi(v.w);
    }
    uint4 o = {pack2bf(s[0], s[1]), pack2bf(s[2], s[3]),
               pack2bf(s[4], s[5]), pack2bf(s[6], s[7])};
    ((uint4*)out)[i] = o;
}

// Reduce SK bf16 partial planes + bias -> f32 (row length 4096)
__global__ __launch_bounds__(256) void reduce_f32_bias(const short* __restrict__ P,
                                                       size_t MN, int SK,
                                                       const float* __restrict__ bias,
                                                       float* __restrict__ out) {
    size_t i = blockIdx.x * 256u + threadIdx.x;
    const uint4* P4 = (const uint4*)P;
    size_t stride = MN >> 3;
    float s[8] = {0,0,0,0,0,0,0,0};
    for (int z = 0; z < SK; ++z) {
        uint4 v = P4[(size_t)z * stride + i];
        s[0] += bflo(v.x); s[1] += bfhi(v.x);
        s[2] += bflo(v.y); s[3] += bfhi(v.y);
        s[4] += bflo(v.z); s[5] += bfhi(v.z);
        s[6] += bflo(v.w); s[7] += bfhi(v.w);
    }
    const float4* b4 = (const float4*)(bias + ((i & 511) << 3));
    float4 b0 = b4[0], b1 = b4[1];
    ((float4*)out)[i * 2]     = (float4){s[0] + b0.x, s[1] + b0.y, s[2] + b0.z, s[3] + b0.w};
    ((float4*)out)[i * 2 + 1] = (float4){s[4] + b1.x, s[5] + b1.y, s[6] + b1.z, s[7] + b1.w};
}

// ---------------------------------------------------------------------------
// Direct (non-split-K) GEMM for the small-ws fallback path
// ---------------------------------------------------------------------------
template <bool OUT_F32>
__global__ __launch_bounds__(256, 4) void gemm_direct(
    const short* __restrict__ A, int lda,
    const short* __restrict__ B, int ldb,
    void* __restrict__ Cv, int ldc,
    const float* __restrict__ bias, int K)
{
    __shared__ __align__(16) short As[128 * 64];
    __shared__ __align__(16) short Bs[128 * 64];

    f32x4 acc[4][4];
    #pragma unroll
    for (int i = 0; i < 4; ++i)
        #pragma unroll
        for (int j = 0; j < 4; ++j)
            acc[i][j] = (f32x4){0.f, 0.f, 0.f, 0.f};

    const int bm = blockIdx.y << 7;
    const int bn = blockIdx.x << 7;
    tile_core(A, lda, B, ldb, K, As, Bs, bm, bn, acc);

    const int tid  = threadIdx.x;
    const int wave = tid >> 6;
    const int lane = tid & 63;
    const int wm   = (wave >> 1) << 6;
    const int wn   = (wave & 1) << 6;
    const int l16  = lane & 15;
    const int quad = lane >> 4;

    if (OUT_F32) {
        float* C = (float*)Cv;
        #pragma unroll
        for (int nt = 0; nt < 4; ++nt) {
            int col = bn + wn + nt * 16 + l16;
            float bv = bias ? bias[col] : 0.f;
            #pragma unroll
            for (int mt = 0; mt < 4; ++mt) {
                int rowb = bm + wm + mt * 16 + quad * 4;
                #pragma unroll
                for (int r = 0; r < 4; ++r)
                    C[(size_t)(rowb + r) * ldc + col] = acc[mt][nt][r] + bv;
            }
        }
    } else {
        store_tile_bf16(acc, (short*)Cv, ldc, bm, bn);
    }
}

extern "C" void kernel_launch(void* const* d_in, const int* in_sizes, int n_in,
                              void* d_out, int out_size, void* d_ws, size_t ws_size,
                              hipStream_t stream) {
    const float* x    = (const float*)d_in[0];
    const float* Ur   = (const float*)d_in[1];
    const float* Ui   = (const float*)d_in[2];
    const float* S    = (const float*)d_in[3];
    const float* Vr   = (const float*)d_in[4];
    const float* Vi   = (const float*)d_in[5];
    const float* bias = (const float*)d_in[6];
    float* out = (float*)d_out;

    short* ws   = (short*)d_ws;
    short* x_bf = ws;                                  // 1024*4096
    short* B1   = x_bf + (size_t)1024 * 4096;          // 2048*4096
    short* Vcat = B1   + (size_t)2048 * 4096;          // 2048*2048
    short* B2t  = Vcat + (size_t)2048 * 2048;          // 2048*1024
    short* Ucat = B2t  + (size_t)2048 * 1024;          // 4096*1024
    short* Xp   = Ucat + (size_t)4096 * 1024;          // 1024*2048
    short* T1   = Xp   + (size_t)1024 * 2048;          // 1024*2048
    short* M2   = T1   + (size_t)1024 * 2048;          // 4096*2048
    short* Pp   = M2   + (size_t)4096 * 2048;          // partials: 16.78M shorts

    const size_t need = (size_t)((char*)(Pp + (size_t)8 * 1024 * 2048) - (char*)d_ws);

    aux_all8<<<dim3(11264), 256, 0, stream>>>(
        x, Ur, Ui, S, Vr, Vi, x_bf, B1, Vcat, B2t, Ucat);

    if (ws_size >= need) {
        // Merged: stage-1 split-K (SK=8, Kpart=512) + M2 (K=1024, direct)
        gemm_s1_m2<<<dim3(16, 8, 12), 256, 0, stream>>>(
            x_bf, B1, Pp, Ucat, B2t, M2);
        reduce_bf<<<dim3(1024), 256, 0, stream>>>(
            Pp, (size_t)1024 * 2048, 8, Xp);

        // Stage 2: T1 = X' @ Vcat^T (SK=8, Kpart=256 -> 1024 blocks)
        gemm_sk<<<dim3(16, 8, 8), 256, 0, stream>>>(
            Xp, 2048, Vcat, 2048, Pp, 2048, (size_t)1024 * 2048, 256);
        reduce_bf<<<dim3(1024), 256, 0, stream>>>(
            Pp, (size_t)1024 * 2048, 8, T1);

        // Final: out = T1 @ M2^T + bias (SK=4, Kpart=512 -> 1024 blocks)
        gemm_sk<<<dim3(32, 8, 4), 256, 0, stream>>>(
            T1, 2048, M2, 2048, Pp, 4096, (size_t)1024 * 4096, 512);
        reduce_f32_bias<<<dim3(2048), 256, 0, stream>>>(
            Pp, (size_t)1024 * 4096, 4, bias, out);
    } else {
        // Fallback: all-direct GEMM chain (no partials needed)
        gemm_direct<false><<<dim3(16, 8), 256, 0, stream>>>(
            x_bf, 4096, B1, 4096, Xp, 2048, nullptr, 4096);
        gemm_direct<false><<<dim3(16, 8), 256, 0, stream>>>(
            Xp, 2048, Vcat, 2048, T1, 2048, nullptr, 2048);
        gemm_direct<false><<<dim3(16, 32), 256, 0, stream>>>(
            Ucat, 1024, B2t, 1024, M2, 2048, nullptr, 1024);
        gemm_direct<true><<<dim3(32, 8), 256, 0, stream>>>(
            T1, 2048, M2, 2048, out, 4096, bias, 2048);
    }
}

// Round 7
// 207.007 us; speedup vs baseline: 3.7448x; 1.0187x over previous
//
#include <hip/hip_runtime.h>
#include <math.h>
#include <stdint.h>

#define PI2 6.28318530717958647692f

typedef __bf16 bf16x8 __attribute__((ext_vector_type(8)));
typedef float f32x4 __attribute__((ext_vector_type(4)));

typedef __attribute__((address_space(1))) const void gvoid_t;
typedef __attribute__((address_space(3))) void lvoid_t;

__device__ __forceinline__ void g2l16(const void* g, void* l) {
    __builtin_amdgcn_global_load_lds(
        reinterpret_cast<gvoid_t*>(reinterpret_cast<uintptr_t>(g)),
        reinterpret_cast<lvoid_t*>(reinterpret_cast<uintptr_t>(l)),
        16, 0, 0);
}

__device__ __forceinline__ short f2bf(float f) {
    unsigned u = __float_as_uint(f);
    u += 0x7FFFu + ((u >> 16) & 1u);          // round-to-nearest-even
    return (short)(u >> 16);
}

__device__ __forceinline__ unsigned pack2bf(float a, float b) {
    return (unsigned)(unsigned short)f2bf(a) |
           ((unsigned)(unsigned short)f2bf(b) << 16);
}

__device__ __forceinline__ float bflo(unsigned v) { return __uint_as_float(v << 16); }
__device__ __forceinline__ float bfhi(unsigned v) { return __uint_as_float(v & 0xFFFF0000u); }

// ---------------------------------------------------------------------------
// Fused aux kernel (round-6 proven), 8 elements per thread.
// ---------------------------------------------------------------------------
__global__ __launch_bounds__(256) void aux_all8(
    const float* __restrict__ x,
    const float* __restrict__ Ur, const float* __restrict__ Ui,
    const float* __restrict__ S,
    const float* __restrict__ Vr, const float* __restrict__ Vi,
    short* __restrict__ x_bf, short* __restrict__ B1,
    short* __restrict__ Vcat, short* __restrict__ B2t,
    short* __restrict__ Ucat)
{
    unsigned gid = blockIdx.x * 256u + threadIdx.x;
    unsigned i8  = gid * 8u;
    if (i8 < 4194304u) {
        const float4* s4 = (const float4*)(x + i8);
        float4 a = s4[0], b = s4[1];
        uint4 o = {pack2bf(a.x, a.y), pack2bf(a.z, a.w),
                   pack2bf(b.x, b.y), pack2bf(b.z, b.w)};
        *(uint4*)(x_bf + i8) = o;
    } else if (i8 < 12582912u) {
        unsigned i = i8 - 4194304u;
        int c = i >> 12, j0 = i & 4095;
        const float inv_n = 1.0f / 4096.0f;
        float v[8];
        if (c < 1024) {
            if (c == 0) {
                #pragma unroll
                for (int u = 0; u < 8; ++u) v[u] = inv_n;
            } else {
                #pragma unroll
                for (int u = 0; u < 8; ++u) {
                    int t = (c * (j0 + u)) & 4095;
                    v[u] = 2.0f * inv_n * cosf((float)t * (PI2 / 4096.0f));
                }
            }
        } else {
            int m = c - 1024;
            #pragma unroll
            for (int u = 0; u < 8; ++u) {
                int t = (m * (j0 + u)) & 4095;
                v[u] = -2.0f * inv_n * sinf((float)t * (PI2 / 4096.0f));
            }
        }
        uint4 o = {pack2bf(v[0], v[1]), pack2bf(v[2], v[3]),
                   pack2bf(v[4], v[5]), pack2bf(v[6], v[7])};
        *(uint4*)(B1 + i) = o;
    } else if (i8 < 16777216u) {
        unsigned i = i8 - 12582912u;
        int t = i >> 11, c = i & 2047;
        const float* src = (c < 1024) ? (Vr + t * 1024 + c)
                                      : (Vi + t * 1024 + (c - 1024));
        float4 a = ((const float4*)src)[0], b = ((const float4*)src)[1];
        uint4 o = {pack2bf(a.x, a.y), pack2bf(a.z, a.w),
                   pack2bf(b.x, b.y), pack2bf(b.z, b.w)};
        *(uint4*)(Vcat + i) = o;
    } else if (i8 < 18874368u) {
        unsigned i = i8 - 16777216u;
        int k = i >> 10, p0 = i & 1023;
        float sk = S[k];
        const float inv_n = 1.0f / 2048.0f;
        float v[8];
        #pragma unroll
        for (int u = 0; u < 8; ++u) {
            int p = p0 + u;
            float val;
            if (p == 0) val = inv_n;
            else if (p < 512) {
                int t = (p * k) & 2047;
                val = 2.0f * inv_n * cosf((float)t * (PI2 / 2048.0f));
            } else {
                int q = p - 512;
                int t = (q * k) & 2047;
                val = -2.0f * inv_n * sinf((float)t * (PI2 / 2048.0f));
            }
            v[u] = val * sk;
        }
        uint4 o = {pack2bf(v[0], v[1]), pack2bf(v[2], v[3]),
                   pack2bf(v[4], v[5]), pack2bf(v[6], v[7])};
        *(uint4*)(B2t + i) = o;
    } else {
        unsigned i = i8 - 18874368u;
        int o_ = i >> 10, c = i & 1023;
        const float* src = (c < 512) ? (Ur + o_ * 512 + c)
                                     : (Ui + o_ * 512 + (c - 512));
        float4 a = ((const float4*)src)[0], b = ((const float4*)src)[1];
        uint4 o = {pack2bf(a.x, a.y), pack2bf(a.z, a.w),
                   pack2bf(b.x, b.y), pack2bf(b.z, b.w)};
        *(uint4*)(Ucat + i) = o;
    }
}

// ---------------------------------------------------------------------------
// Shared 128x128 MFMA tile core, BK=64, XOR-swizzled LDS (round-4 proven).
// ---------------------------------------------------------------------------
__device__ __forceinline__ void tile_core(
    const short* __restrict__ A, int lda,
    const short* __restrict__ B, int ldb, int K,
    short* As, short* Bs, int bm, int bn, f32x4 (&acc)[4][4])
{
    const int tid  = threadIdx.x;
    const int wave = tid >> 6;
    const int lane = tid & 63;
    const int wm   = (wave >> 1) << 6;
    const int wn   = (wave & 1) << 6;
    const int l16  = lane & 15;
    const int quad = lane >> 4;
    const int rk   = l16 & 7;

    int aoff[4], boff[4], loff[4];
    #pragma unroll
    for (int p = 0; p < 4; ++p) {
        int L   = p * 256 + wave * 64 + lane;
        int row = L >> 3;
        int swz = (L & 7) ^ (row & 7);
        aoff[p] = (bm + row) * lda + swz * 8;
        boff[p] = (bn + row) * ldb + swz * 8;
        loff[p] = L * 8;
    }

    for (int k0 = 0; k0 < K; k0 += 64) {
        __syncthreads();
        #pragma unroll
        for (int p = 0; p < 4; ++p) g2l16(A + aoff[p] + k0, As + loff[p]);
        #pragma unroll
        for (int p = 0; p < 4; ++p) g2l16(B + boff[p] + k0, Bs + loff[p]);
        __syncthreads();

        #pragma unroll
        for (int h = 0; h < 2; ++h) {
            const int cs8 = ((((h << 2) | quad) ^ rk) << 3);
            bf16x8 b[4];
            #pragma unroll
            for (int nt = 0; nt < 4; ++nt)
                b[nt] = *(const bf16x8*)(Bs + (wn + nt * 16 + l16) * 64 + cs8);
            #pragma unroll
            for (int mt = 0; mt < 4; ++mt) {
                bf16x8 a = *(const bf16x8*)(As + (wm + mt * 16 + l16) * 64 + cs8);
                #pragma unroll
                for (int nt = 0; nt < 4; ++nt)
                    acc[mt][nt] = __builtin_amdgcn_mfma_f32_16x16x32_bf16(
                        a, b[nt], acc[mt][nt], 0, 0, 0);
            }
        }
    }
}

// Row-major bf16 store (used by M2 and the fallback path)
__device__ __forceinline__ void store_tile_bf16(
    f32x4 (&acc)[4][4], short* __restrict__ C, int ldc, int bm, int bn)
{
    const int tid  = threadIdx.x;
    const int wave = tid >> 6;
    const int lane = tid & 63;
    const int wm   = (wave >> 1) << 6;
    const int wn   = (wave & 1) << 6;
    const int l16  = lane & 15;
    const int quad = lane >> 4;
    #pragma unroll
    for (int nt = 0; nt < 4; ++nt) {
        int col = bn + wn + nt * 16 + l16;
        #pragma unroll
        for (int mt = 0; mt < 4; ++mt) {
            int rowb = bm + wm + mt * 16 + quad * 4;
            #pragma unroll
            for (int r = 0; r < 4; ++r)
                C[(size_t)(rowb + r) * ldc + col] = f2bf(acc[mt][nt][r]);
        }
    }
}

// Fragment-layout store: 8 coalesced uint4 per thread.
// Chunk c (0..7): nt = c>>1, mt0 = (c&1)*2; uint4 = acc[mt0][nt][0..3] ++
// acc[mt0+1][nt][0..3]. Plane slot (uint4): tile*2048 + c*256 + tid.
__device__ __forceinline__ void store_frag(
    f32x4 (&acc)[4][4], short* __restrict__ planeTile)
{
    uint4* p = (uint4*)planeTile;
    const int tid = threadIdx.x;
    #pragma unroll
    for (int c = 0; c < 8; ++c) {
        int nt = c >> 1, mt0 = (c & 1) * 2;
        uint4 o = {pack2bf(acc[mt0][nt][0],     acc[mt0][nt][1]),
                   pack2bf(acc[mt0][nt][2],     acc[mt0][nt][3]),
                   pack2bf(acc[mt0 + 1][nt][0], acc[mt0 + 1][nt][1]),
                   pack2bf(acc[mt0 + 1][nt][2], acc[mt0 + 1][nt][3])};
        p[c * 256 + tid] = o;
    }
}

// ---------------------------------------------------------------------------
// Merged dispatch, grid (16,8,8) = 1024 blocks = 4/CU exactly:
//   z<4  -> stage-1 split-K (SK=4, Kpart=1024), frag-layout partials
//   z>=4 -> M2 = Ucat @ B2t^T (4096x2048, K=1024), row-major direct
// ---------------------------------------------------------------------------
__global__ __launch_bounds__(256, 4) void gemm_s1_m2(
    const short* __restrict__ x_bf, const short* __restrict__ B1,
    short* __restrict__ Pp,
    const short* __restrict__ Ucat, const short* __restrict__ B2t,
    short* __restrict__ M2)
{
    __shared__ __align__(16) short As[128 * 64];
    __shared__ __align__(16) short Bs[128 * 64];

    f32x4 acc[4][4];
    #pragma unroll
    for (int i = 0; i < 4; ++i)
        #pragma unroll
        for (int j = 0; j < 4; ++j)
            acc[i][j] = (f32x4){0.f, 0.f, 0.f, 0.f};

    const int z = blockIdx.z;
    if (z < 4) {
        const int bm = blockIdx.y << 7;
        const int bn = blockIdx.x << 7;
        const int tile = blockIdx.y * 16 + blockIdx.x;
        tile_core(x_bf + z * 1024, 4096, B1 + z * 1024, 4096, 1024,
                  As, Bs, bm, bn, acc);
        store_frag(acc, Pp + (size_t)z * 2097152 + (size_t)tile * 16384);
    } else {
        const int bm = (blockIdx.y + ((z - 4) << 3)) << 7;   // row tile 0..31
        const int bn = blockIdx.x << 7;
        tile_core(Ucat, 1024, B2t, 1024, 1024, As, Bs, bm, bn, acc);
        store_tile_bf16(acc, M2, 2048, bm, bn);
    }
}

// ---------------------------------------------------------------------------
// Split-K GEMM into fragment-layout bf16 partial planes
// ---------------------------------------------------------------------------
__global__ __launch_bounds__(256, 4) void gemm_sk_frag(
    const short* __restrict__ A, int lda,
    const short* __restrict__ B, int ldb,
    short* __restrict__ P, size_t planeShorts, int Kpart)
{
    __shared__ __align__(16) short As[128 * 64];
    __shared__ __align__(16) short Bs[128 * 64];

    f32x4 acc[4][4];
    #pragma unroll
    for (int i = 0; i < 4; ++i)
        #pragma unroll
        for (int j = 0; j < 4; ++j)
            acc[i][j] = (f32x4){0.f, 0.f, 0.f, 0.f};

    const int bm = blockIdx.y << 7;
    const int bn = blockIdx.x << 7;
    const int z  = blockIdx.z;
    const int tile = blockIdx.y * gridDim.x + blockIdx.x;
    tile_core(A + (size_t)z * Kpart, lda, B + (size_t)z * Kpart, ldb, Kpart,
              As, Bs, bm, bn, acc);
    store_frag(acc, P + (size_t)z * planeShorts + (size_t)tile * 16384);
}

// ---------------------------------------------------------------------------
// Reduce SK fragment-layout planes -> row-major output.
// Grid = tiles*4 blocks; block (tile, q) handles chunks {2q, 2q+1} (nt = q).
// Reads coalesced uint4; writes sector-full scalar stores (16 consecutive
// cols per quad-row). OUT_F32 adds bias.
// ---------------------------------------------------------------------------
template <bool OUT_F32>
__global__ __launch_bounds__(256) void reduce_frag(
    const short* __restrict__ P, size_t planeShorts, int SK,
    int tilesX, void* __restrict__ Out, int ldc,
    const float* __restrict__ bias)
{
    const int blk  = blockIdx.x;
    const int tile = blk >> 2;
    const int q    = blk & 3;
    const int bm   = (tile / tilesX) << 7;
    const int bn   = (tile % tilesX) << 7;

    const int tid  = threadIdx.x;
    const int wave = tid >> 6;
    const int lane = tid & 63;
    const int wm   = (wave >> 1) << 6;
    const int wn   = (wave & 1) << 6;
    const int l16  = lane & 15;
    const int quad = lane >> 4;

    const uint4* P4 = (const uint4*)P;
    const size_t planeU4 = planeShorts >> 3;
    const size_t base = (size_t)tile * 2048 + tid;

    const int col = bn + wn + q * 16 + l16;     // nt == q, fixed per block
    float bv = 0.f;
    if (OUT_F32) bv = bias[col];

    #pragma unroll
    for (int cc = 0; cc < 2; ++cc) {
        const int c = q * 2 + cc;
        float f[8] = {0, 0, 0, 0, 0, 0, 0, 0};
        for (int z = 0; z < SK; ++z) {
            uint4 v = P4[(size_t)z * planeU4 + base + c * 256];
            f[0] += bflo(v.x); f[1] += bfhi(v.x);
            f[2] += bflo(v.y); f[3] += bfhi(v.y);
            f[4] += bflo(v.z); f[5] += bfhi(v.z);
            f[6] += bflo(v.w); f[7] += bfhi(v.w);
        }
        const int mt0 = (c & 1) * 2;
        #pragma unroll
        for (int j = 0; j < 8; ++j) {
            int mt  = mt0 + (j >> 2);
            int row = bm + wm + mt * 16 + quad * 4 + (j & 3);
            if (OUT_F32)
                ((float*)Out)[(size_t)row * ldc + col] = f[j] + bv;
            else
                ((short*)Out)[(size_t)row * ldc + col] = f2bf(f[j]);
        }
    }
}

// ---------------------------------------------------------------------------
// Direct GEMM for the small-ws fallback path (round-6 proven)
// ---------------------------------------------------------------------------
template <bool OUT_F32>
__global__ __launch_bounds__(256, 4) void gemm_direct(
    const short* __restrict__ A, int lda,
    const short* __restrict__ B, int ldb,
    void* __restrict__ Cv, int ldc,
    const float* __restrict__ bias, int K)
{
    __shared__ __align__(16) short As[128 * 64];
    __shared__ __align__(16) short Bs[128 * 64];

    f32x4 acc[4][4];
    #pragma unroll
    for (int i = 0; i < 4; ++i)
        #pragma unroll
        for (int j = 0; j < 4; ++j)
            acc[i][j] = (f32x4){0.f, 0.f, 0.f, 0.f};

    const int bm = blockIdx.y << 7;
    const int bn = blockIdx.x << 7;
    tile_core(A, lda, B, ldb, K, As, Bs, bm, bn, acc);

    const int tid  = threadIdx.x;
    const int wave = tid >> 6;
    const int lane = tid & 63;
    const int wm   = (wave >> 1) << 6;
    const int wn   = (wave & 1) << 6;
    const int l16  = lane & 15;
    const int quad = lane >> 4;

    if (OUT_F32) {
        float* C = (float*)Cv;
        #pragma unroll
        for (int nt = 0; nt < 4; ++nt) {
            int col = bn + wn + nt * 16 + l16;
            float bv = bias ? bias[col] : 0.f;
            #pragma unroll
            for (int mt = 0; mt < 4; ++mt) {
                int rowb = bm + wm + mt * 16 + quad * 4;
                #pragma unroll
                for (int r = 0; r < 4; ++r)
                    C[(size_t)(rowb + r) * ldc + col] = acc[mt][nt][r] + bv;
            }
        }
    } else {
        store_tile_bf16(acc, (short*)Cv, ldc, bm, bn);
    }
}

extern "C" void kernel_launch(void* const* d_in, const int* in_sizes, int n_in,
                              void* d_out, int out_size, void* d_ws, size_t ws_size,
                              hipStream_t stream) {
    const float* x    = (const float*)d_in[0];
    const float* Ur   = (const float*)d_in[1];
    const float* Ui   = (const float*)d_in[2];
    const float* S    = (const float*)d_in[3];
    const float* Vr   = (const float*)d_in[4];
    const float* Vi   = (const float*)d_in[5];
    const float* bias = (const float*)d_in[6];
    float* out = (float*)d_out;

    short* ws   = (short*)d_ws;
    short* x_bf = ws;                                  // 1024*4096
    short* B1   = x_bf + (size_t)1024 * 4096;          // 2048*4096
    short* Vcat = B1   + (size_t)2048 * 4096;          // 2048*2048
    short* B2t  = Vcat + (size_t)2048 * 2048;          // 2048*1024
    short* Ucat = B2t  + (size_t)2048 * 1024;          // 4096*1024
    short* Xp   = Ucat + (size_t)4096 * 1024;          // 1024*2048
    short* T1   = Xp   + (size_t)1024 * 2048;          // 1024*2048
    short* M2   = T1   + (size_t)1024 * 2048;          // 4096*2048
    short* Pp   = M2   + (size_t)4096 * 2048;          // partials: 16.78M shorts

    const size_t need = (size_t)((char*)(Pp + (size_t)8 * 1024 * 2048) - (char*)d_ws);

    aux_all8<<<dim3(11264), 256, 0, stream>>>(
        x, Ur, Ui, S, Vr, Vi, x_bf, B1, Vcat, B2t, Ucat);

    if (ws_size >= need) {
        // s1 (SK=4, Kpart=1024, frag partials) + M2 (direct) : 1024 blocks
        gemm_s1_m2<<<dim3(16, 8, 8), 256, 0, stream>>>(
            x_bf, B1, Pp, Ucat, B2t, M2);
        reduce_frag<false><<<dim3(512), 256, 0, stream>>>(
            Pp, (size_t)2097152, 4, 16, Xp, 2048, nullptr);

        // Stage 2: T1 = X' @ Vcat^T (SK=4, Kpart=512 -> 512 blocks)
        gemm_sk_frag<<<dim3(16, 8, 4), 256, 0, stream>>>(
            Xp, 2048, Vcat, 2048, Pp, (size_t)2097152, 512);
        reduce_frag<false><<<dim3(512), 256, 0, stream>>>(
            Pp, (size_t)2097152, 4, 16, T1, 2048, nullptr);

        // Final: out = T1 @ M2^T + bias (SK=4, Kpart=512 -> 1024 blocks)
        gemm_sk_frag<<<dim3(32, 8, 4), 256, 0, stream>>>(
            T1, 2048, M2, 2048, Pp, (size_t)4194304, 512);
        reduce_frag<true><<<dim3(1024), 256, 0, stream>>>(
            Pp, (size_t)4194304, 4, 32, out, 4096, bias);
    } else {
        gemm_direct<false><<<dim3(16, 8), 256, 0, stream>>>(
            x_bf, 4096, B1, 4096, Xp, 2048, nullptr, 4096);
        gemm_direct<false><<<dim3(16, 8), 256, 0, stream>>>(
            Xp, 2048, Vcat, 2048, T1, 2048, nullptr, 2048);
        gemm_direct<false><<<dim3(16, 32), 256, 0, stream>>>(
            Ucat, 1024, B2t, 1024, M2, 2048, nullptr, 1024);
        gemm_direct<true><<<dim3(32, 8), 256, 0, stream>>>(
            T1, 2048, M2, 2048, out, 4096, bias, 2048);
    }
}